// Round 3
// baseline (846.678 us; speedup 1.0000x reference)
//
#include <hip/hip_runtime.h>
#include <cstdint>
#include <cstddef>

#define K_SAMP 50
#define CAP    4096
#define NFEAT  90
#define RROI   256
#define MROWS  256
#define CHUNK  1024
#define FROW   (K_SAMP * NFEAT)   // 4500
#define NB     256                // fused-MLP resident grid (1 block per CU)

// ---------------------------------------------------------------------------
// 1) Per-chunk ROI histogram + global per-ROI counts. Reads idx exactly once.
// ---------------------------------------------------------------------------
__global__ __launch_bounds__(256) void hist_kernel(
    const int* __restrict__ idx, int* __restrict__ H, int* __restrict__ counts,
    int N, int nC)
{
    __shared__ int h[RROI];
    const int c = blockIdx.x, tid = threadIdx.x;
    h[tid] = 0;
    __syncthreads();
    int p0 = c * CHUNK + tid * 4;
    if (p0 + 3 < N) {
        int4 v = *reinterpret_cast<const int4*>(idx + p0);
        atomicAdd(&h[v.x], 1); atomicAdd(&h[v.y], 1);
        atomicAdd(&h[v.z], 1); atomicAdd(&h[v.w], 1);
    } else {
        #pragma unroll
        for (int j = 0; j < 4; j++)
            if (p0 + j < N) atomicAdd(&h[idx[p0 + j]], 1);
    }
    __syncthreads();
    int v = h[tid];
    H[tid * nC + c] = v;            // layout [roi][chunk]
    if (v) atomicAdd(&counts[tid], v);
}

// ---------------------------------------------------------------------------
// block-wide exclusive scan over 256 values (4 waves)
// ---------------------------------------------------------------------------
__device__ __forceinline__ int block_scan256(int v, int& total, int* s_w, int tid)
{
    const int lane = tid & 63, w = tid >> 6;
    int inc = v;
    #pragma unroll
    for (int d = 1; d < 64; d <<= 1) {
        int o = __shfl_up(inc, (unsigned)d);
        if (lane >= d) inc += o;
    }
    if (lane == 63) s_w[w] = inc;
    __syncthreads();
    int woff = 0;
    #pragma unroll
    for (int j = 0; j < 4; j++) woff += (j < w) ? s_w[j] : 0;
    total = s_w[0] + s_w[1] + s_w[2] + s_w[3];
    __syncthreads();
    return woff + inc - v;
}

// ---------------------------------------------------------------------------
// 2) One block per ROI: exclusive scan of its chunk hist + global ROI offset.
// ---------------------------------------------------------------------------
__global__ __launch_bounds__(256) void chunk_scan_kernel(
    int* __restrict__ H, const int* __restrict__ counts, int* __restrict__ offs, int nC)
{
    __shared__ int s_w[4];
    __shared__ int s_scan[RROI];
    const int r = blockIdx.x, tid = threadIdx.x;
    int tot;
    int e = block_scan256(counts[tid], tot, s_w, tid);
    s_scan[tid] = e;
    __syncthreads();
    const int off = s_scan[r];
    int v0 = (tid < nC) ? H[r * nC + tid] : 0;
    int t0;
    int e0 = block_scan256(v0, t0, s_w, tid);
    if (tid < nC) H[r * nC + tid] = off + e0;
    int c2 = 256 + tid;
    int v1 = (c2 < nC) ? H[r * nC + c2] : 0;
    int t1;
    int e1 = block_scan256(v1, t1, s_w, tid);
    if (c2 < nC) H[r * nC + c2] = off + t0 + e1;
    if (tid == 0) offs[r] = off;
}

// ---------------------------------------------------------------------------
// 3) Stable scatter: each point -> its ROI segment, original order preserved.
// ---------------------------------------------------------------------------
__global__ __launch_bounds__(256) void scatter_kernel(
    const int* __restrict__ idx, const float* __restrict__ coords,
    const int* __restrict__ H, int* __restrict__ sGid,
    float* __restrict__ sXc, float* __restrict__ sYc, float* __restrict__ sZc,
    int N, int nC)
{
    __shared__ int s_base[RROI];
    const int c = blockIdx.x, tid = threadIdx.x;
    const int lane = tid & 63, wid = tid >> 6;
    s_base[tid] = H[tid * nC + c];
    int roiA[4]; float cxA[4], cyA[4], czA[4]; bool valA[4];
    #pragma unroll
    for (int j = 0; j < 4; j++) {
        int p = c * CHUNK + j * 256 + tid;
        bool v = p < N;
        valA[j] = v;
        roiA[j] = v ? idx[p] : 0;
        float x = 0.f, y = 0.f, z = 0.f;
        if (v) { x = coords[(size_t)p*3]; y = coords[(size_t)p*3+1]; z = coords[(size_t)p*3+2]; }
        cxA[j] = x; cyA[j] = y; czA[j] = z;
    }
    __syncthreads();
    #pragma unroll
    for (int j = 0; j < 4; j++) {
        #pragma unroll
        for (int w = 0; w < 4; w++) {
            if (wid == w) {
                bool v = valA[j];
                int roi = roiA[j];
                unsigned long long vm = __ballot(v);
                unsigned long long match = vm;
                #pragma unroll
                for (int b = 0; b < 8; b++) {
                    unsigned long long vote = __ballot((roi >> b) & 1);
                    match &= ((roi >> b) & 1) ? vote : ~vote;
                }
                int leader = match ? (__ffsll(match) - 1) : 0;
                int gsz  = (int)__popcll(match);
                int rank = (int)__popcll(match & ((1ull << lane) - 1ull));
                int basev = 0;
                if (match && lane == leader) {
                    basev = s_base[roi];
                    s_base[roi] = basev + gsz;
                }
                basev = __shfl(basev, leader);
                if (v) {
                    int dest = basev + rank;
                    int p = c * CHUNK + j * 256 + tid;
                    sGid[dest] = p;
                    sXc[dest] = cxA[j]; sYc[dest] = cyA[j]; sZc[dest] = czA[j];
                }
            }
            __syncthreads();
        }
    }
}

// ---------------------------------------------------------------------------
// 4) FPS per ROI (register distances) + feature gather (verified round 2).
// ---------------------------------------------------------------------------
__global__ __launch_bounds__(512) void fps_feat_kernel(
    const int* __restrict__ offs, const int* __restrict__ counts,
    const float* __restrict__ sXc, const float* __restrict__ sYc,
    const float* __restrict__ sZc, const int* __restrict__ sGid,
    const float* __restrict__ feats, float* __restrict__ feat_out)
{
    __shared__ float sx[CAP], sy[CAP], sz[CAP];
    __shared__ int   sg[CAP];
    __shared__ int   s_samp[K_SAMP];
    __shared__ float s_rv[8];
    __shared__ int   s_ri[8];
    __shared__ int   s_last;

    const int r = blockIdx.x, tid = threadIdx.x;
    const int lane = tid & 63, wid = tid >> 6;
    const int off = offs[r];
    int count = counts[r]; if (count > CAP) count = CAP;

    float rx[8], ry[8], rz[8], rd[8];
    #pragma unroll
    for (int j = 0; j < 8; j++) {
        int i = j * 512 + tid;
        bool v = i < count;
        float x = 0.f, y = 0.f, z = 0.f;
        if (v) {
            x = sXc[off + i]; y = sYc[off + i]; z = sZc[off + i];
            sg[i] = sGid[off + i];
        }
        rx[j] = x; ry[j] = y; rz[j] = z;
        rd[j] = v ? 1e10f : -1.0f;
        sx[i] = x; sy[i] = y; sz[i] = z;
    }
    if (tid == 0) { s_samp[0] = 0; s_last = 0; }
    __syncthreads();

    if (count > 0) {
        int last = 0;
        for (int k = 1; k < K_SAMP; k++) {
            float lx = sx[last], ly = sy[last], lz = sz[last];
            float bv = -3.0e38f; int bi = 0x7fffffff;
            #pragma unroll
            for (int j = 0; j < 8; j++) {
                float dx = rx[j] - lx, dy = ry[j] - ly, dz = rz[j] - lz;
                float d = __fadd_rn(__fadd_rn(__fmul_rn(dx,dx), __fmul_rn(dy,dy)),
                                    __fmul_rn(dz,dz));
                float nd = fminf(rd[j], d);
                rd[j] = nd;
                int i = j * 512 + tid;
                if (nd > bv || (nd == bv && i < bi)) { bv = nd; bi = i; }
            }
            #pragma unroll
            for (int m = 32; m > 0; m >>= 1) {
                float ov = __shfl_xor(bv, m);
                int   oi = __shfl_xor(bi, m);
                if (ov > bv || (ov == bv && oi < bi)) { bv = ov; bi = oi; }
            }
            if (lane == 0) { s_rv[wid] = bv; s_ri[wid] = bi; }
            __syncthreads();
            if (tid == 0) {
                #pragma unroll
                for (int j = 1; j < 8; j++)
                    if (s_rv[j] > bv || (s_rv[j] == bv && s_ri[j] < bi)) {
                        bv = s_rv[j]; bi = s_ri[j];
                    }
                s_samp[k] = bi; s_last = bi;
            }
            __syncthreads();
            last = s_last;
        }
    }
    __syncthreads();

    for (int t = tid; t < FROW; t += 512) {
        int s = t / NFEAT;
        int f = t - s * NFEAT;
        float v = 0.f;
        if (count > 0) {
            int gid = sg[s_samp[s]];
            v = feats[(size_t)gid * NFEAT + f];
        }
        feat_out[(size_t)r * FROW + t] = v;
    }
}

// ---------------------------------------------------------------------------
// 5) Fused MLP: one resident-grid kernel (256 blocks == 256 CUs, all
//    co-resident: 256 thr, 8.1 KB LDS, low VGPR). Software global barrier
//    with monotonically increasing device-scope counter + threadfences.
// ---------------------------------------------------------------------------
__device__ __forceinline__ void gbar(int* bar, int target)
{
    __syncthreads();
    if (threadIdx.x == 0) {
        __threadfence();   // release: publish this block's writes
        __hip_atomic_fetch_add(bar, 1, __ATOMIC_ACQ_REL, __HIP_MEMORY_SCOPE_AGENT);
        while (__hip_atomic_load(bar, __ATOMIC_ACQUIRE, __HIP_MEMORY_SCOPE_AGENT) < target)
            __builtin_amdgcn_s_sleep(2);
        __threadfence();   // acquire: invalidate for other blocks' writes
    }
    __syncthreads();
}

// split-K GEMM phase: C += A[256,K]*B[K,N] over virtual grid (gx,gy,gz).
// Identical tile math to the verified standalone gemm_splitk.
__device__ __forceinline__ void gemm_phase(
    const float* __restrict__ A, const float* __restrict__ B, float* __restrict__ C,
    int Ncols, int Kdim, int gx, int gy, int gz, int kc,
    float (*As)[64], float (*Bs)[64])
{
    const int vb = blockIdx.x;
    if (vb >= gx * gy * gz) return;
    const int tid = threadIdx.x;
    const int bx = vb % gx;
    const int by = (vb / gx) % gy;
    const int bz = vb / (gx * gy);
    const int bm = by * 64;
    const int bn = bx * 64;
    const int k0 = bz * kc;
    const int k1 = (k0 + kc < Kdim) ? (k0 + kc) : Kdim;
    const int ty = tid >> 4, tx = tid & 15;
    const int am = tid >> 2, ak = (tid & 3) * 4;
    const int bk = tid >> 6, bnn = tid & 63;

    float acc[4][4] = {};
    for (int k = k0; k < k1; k += 16) {
        int arow = bm + am;
        float4 av;
        if (k + ak + 3 < Kdim) {
            av = *reinterpret_cast<const float4*>(A + (size_t)arow * Kdim + k + ak);
        } else {
            av.x = (k+ak+0 < Kdim) ? A[(size_t)arow*Kdim + k+ak+0] : 0.f;
            av.y = (k+ak+1 < Kdim) ? A[(size_t)arow*Kdim + k+ak+1] : 0.f;
            av.z = (k+ak+2 < Kdim) ? A[(size_t)arow*Kdim + k+ak+2] : 0.f;
            av.w = (k+ak+3 < Kdim) ? A[(size_t)arow*Kdim + k+ak+3] : 0.f;
        }
        As[ak+0][am] = av.x; As[ak+1][am] = av.y;
        As[ak+2][am] = av.z; As[ak+3][am] = av.w;
        #pragma unroll
        for (int j = 0; j < 4; j++) {
            int kr = bk + j * 4;
            Bs[kr][bnn] = (k + kr < Kdim) ? B[(size_t)(k + kr) * Ncols + bn + bnn] : 0.f;
        }
        __syncthreads();
        #pragma unroll
        for (int kk = 0; kk < 16; kk++) {
            float4 aq = *reinterpret_cast<const float4*>(&As[kk][ty * 4]);
            float4 bq = *reinterpret_cast<const float4*>(&Bs[kk][tx * 4]);
            float a[4] = {aq.x, aq.y, aq.z, aq.w};
            float b[4] = {bq.x, bq.y, bq.z, bq.w};
            #pragma unroll
            for (int i = 0; i < 4; i++)
                #pragma unroll
                for (int j = 0; j < 4; j++)
                    acc[i][j] = fmaf(a[i], b[j], acc[i][j]);
        }
        __syncthreads();
    }
    #pragma unroll
    for (int i = 0; i < 4; i++)
        #pragma unroll
        for (int j = 0; j < 4; j++)
            atomicAdd(&C[(size_t)(bm + ty*4 + i) * Ncols + (bn + tx*4 + j)], acc[i][j]);
}

// BN phase (block-per-column over 256 rows), optional ReLU; X may equal Y.
__device__ __forceinline__ void bn_phase(
    const float* __restrict__ X, float* __restrict__ Y,
    const float* __restrict__ g, const float* __restrict__ be,
    int C, int relu, float* sred)
{
    const int t = threadIdx.x, lane = t & 63, w = t >> 6;
    for (int c = blockIdx.x; c < C; c += NB) {
        float x = X[(size_t)t * C + c];
        float s = x;
        #pragma unroll
        for (int d = 32; d > 0; d >>= 1) s += __shfl_xor(s, d);
        if (lane == 0) sred[w] = s;
        __syncthreads();
        float m = (sred[0] + sred[1] + sred[2] + sred[3]) * (1.f / MROWS);
        float dv = x - m;
        float q = dv * dv;
        #pragma unroll
        for (int d = 32; d > 0; d >>= 1) q += __shfl_xor(q, d);
        if (lane == 0) sred[4 + w] = q;
        __syncthreads();
        float v = (sred[4] + sred[5] + sred[6] + sred[7]) * (1.f / MROWS);
        float y = g[c] * dv * rsqrtf(v + 1e-5f) + be[c];
        if (relu) y = fmaxf(y, 0.f);
        Y[(size_t)t * C + c] = y;
        __syncthreads();
    }
}

__global__ __launch_bounds__(256) void mlp_fused_kernel(
    const float* __restrict__ feat,
    const float* __restrict__ w1, const float* __restrict__ g1, const float* __restrict__ be1,
    const float* __restrict__ w2, const float* __restrict__ g2, const float* __restrict__ be2,
    const float* __restrict__ w3, const float* __restrict__ g3, const float* __restrict__ be3,
    const float* __restrict__ w4, const float* __restrict__ g4, const float* __restrict__ be4,
    const float* __restrict__ w5, const float* __restrict__ g5, const float* __restrict__ be5,
    float* __restrict__ x1, float* __restrict__ x2, float* __restrict__ x3,
    float* __restrict__ x4, float* __restrict__ x5, float* __restrict__ out,
    int* bar)
{
    __shared__ float As[16][64];
    __shared__ float Bs[16][64];
    __shared__ float sred[8];

    // phase 0: zero all split-K accumulators (x1..x5 contiguous, 458752 floats)
    {
        float4* z = reinterpret_cast<float4*>(x1);
        const int nz = 458752 / 4;
        for (int i = blockIdx.x * 256 + threadIdx.x; i < nz; i += NB * 256)
            z[i] = float4{0.f, 0.f, 0.f, 0.f};
    }
    gbar(bar, 1 * NB);
    gemm_phase(feat, w1, x1, 256, 4500, 4, 4, 16, 288, As, Bs);  gbar(bar, 2 * NB);
    bn_phase(x1, x1, g1, be1, 256, 1, sred);                     gbar(bar, 3 * NB);
    gemm_phase(x1, w2, x2, 256, 256, 4, 4, 4, 64, As, Bs);       gbar(bar, 4 * NB);
    bn_phase(x2, x2, g2, be2, 256, 1, sred);                     gbar(bar, 5 * NB);
    gemm_phase(x2, w3, x3, 512, 256, 8, 4, 4, 64, As, Bs);       gbar(bar, 6 * NB);
    bn_phase(x3, x3, g3, be3, 512, 0, sred);                     gbar(bar, 7 * NB);
    gemm_phase(x3, w4, x4, 256, 512, 4, 4, 8, 64, As, Bs);       gbar(bar, 8 * NB);
    bn_phase(x4, x4, g4, be4, 256, 1, sred);                     gbar(bar, 9 * NB);
    gemm_phase(x4, w5, x5, 512, 256, 8, 4, 4, 64, As, Bs);       gbar(bar, 10 * NB);
    bn_phase(x5, out, g5, be5, 512, 1, sred);
}

// ---------------------------------------------------------------------------
extern "C" void kernel_launch(void* const* d_in, const int* in_sizes, int n_in,
                              void* d_out, int out_size, void* d_ws, size_t ws_size,
                              hipStream_t stream)
{
    (void)n_in; (void)out_size; (void)ws_size;
    const int*   idx    = (const int*)  d_in[1];
    const float* feats  = (const float*)d_in[2];
    const float* coords = (const float*)d_in[3];
    const float* w1 = (const float*)d_in[4];
    const float* g1 = (const float*)d_in[6];  const float* be1 = (const float*)d_in[7];
    const float* w2 = (const float*)d_in[8];
    const float* g2 = (const float*)d_in[10]; const float* be2 = (const float*)d_in[11];
    const float* w3 = (const float*)d_in[12];
    const float* g3 = (const float*)d_in[14]; const float* be3 = (const float*)d_in[15];
    const float* w4 = (const float*)d_in[16];
    const float* g4 = (const float*)d_in[18]; const float* be4 = (const float*)d_in[19];
    const float* w5 = (const float*)d_in[20];
    const float* g5 = (const float*)d_in[22]; const float* be5 = (const float*)d_in[23];
    const int N  = in_sizes[1];
    const int nC = (N + CHUNK - 1) / CHUNK;

    float* ws   = (float*)d_ws;
    float* feat = ws;                        // 1,152,000
    float* x1   = ws + 1152000;              // 65536
    float* x2   = x1 + 65536;                // 65536
    float* x3   = x2 + 65536;                // 131072
    float* x4   = x3 + 131072;               // 65536
    float* x5   = x4 + 65536;                // 131072  (x1..x5 = 458752 floats)
    int*   counts = (int*)(x5 + 131072);     // 256
    int*   bar    = counts + 256;            // 16
    int*   offs   = bar + 16;                // 256
    int*   H      = offs + 256;              // up to 256*1024
    int*   sGid   = H + 256 * 1024;          // N
    float* sXc    = (float*)(sGid + N);      // N
    float* sYc    = sXc + N;                 // N
    float* sZc    = sYc + N;                 // N
    float* out    = (float*)d_out;

    // zero counts + barrier counter (1088 B); accumulators zeroed in-kernel
    hipMemsetAsync(counts, 0, 272 * sizeof(int), stream);

    hist_kernel      <<<nC,  256, 0, stream>>>(idx, H, counts, N, nC);
    chunk_scan_kernel<<<256, 256, 0, stream>>>(H, counts, offs, nC);
    scatter_kernel   <<<nC,  256, 0, stream>>>(idx, coords, H, sGid, sXc, sYc, sZc, N, nC);
    fps_feat_kernel  <<<256, 512, 0, stream>>>(offs, counts, sXc, sYc, sZc, sGid, feats, feat);

    mlp_fused_kernel <<<NB, 256, 0, stream>>>(
        feat, w1, g1, be1, w2, g2, be2, w3, g3, be3, w4, g4, be4, w5, g5, be5,
        x1, x2, x3, x4, x5, out, bar);
}

// Round 4
// 663.163 us; speedup vs baseline: 1.2767x; 1.2767x over previous
//
#include <hip/hip_runtime.h>
#include <cstdint>
#include <cstddef>

#define K_SAMP 50
#define CAP    4096
#define NFEAT  90
#define RROI   256
#define MROWS  256
#define CHUNK  1024
#define FROW   (K_SAMP * NFEAT)   // 4500

// ---------------------------------------------------------------------------
// 1) Per-chunk ROI histogram + global per-ROI counts (verified round 2).
// ---------------------------------------------------------------------------
__global__ __launch_bounds__(256) void hist_kernel(
    const int* __restrict__ idx, int* __restrict__ H, int* __restrict__ counts,
    int N, int nC)
{
    __shared__ int h[RROI];
    const int c = blockIdx.x, tid = threadIdx.x;
    h[tid] = 0;
    __syncthreads();
    int p0 = c * CHUNK + tid * 4;
    if (p0 + 3 < N) {
        int4 v = *reinterpret_cast<const int4*>(idx + p0);
        atomicAdd(&h[v.x], 1); atomicAdd(&h[v.y], 1);
        atomicAdd(&h[v.z], 1); atomicAdd(&h[v.w], 1);
    } else {
        #pragma unroll
        for (int j = 0; j < 4; j++)
            if (p0 + j < N) atomicAdd(&h[idx[p0 + j]], 1);
    }
    __syncthreads();
    int v = h[tid];
    H[tid * nC + c] = v;            // layout [roi][chunk]
    if (v) atomicAdd(&counts[tid], v);
}

// ---------------------------------------------------------------------------
// block-wide exclusive scan over 256 values (4 waves) (verified round 2)
// ---------------------------------------------------------------------------
__device__ __forceinline__ int block_scan256(int v, int& total, int* s_w, int tid)
{
    const int lane = tid & 63, w = tid >> 6;
    int inc = v;
    #pragma unroll
    for (int d = 1; d < 64; d <<= 1) {
        int o = __shfl_up(inc, (unsigned)d);
        if (lane >= d) inc += o;
    }
    if (lane == 63) s_w[w] = inc;
    __syncthreads();
    int woff = 0;
    #pragma unroll
    for (int j = 0; j < 4; j++) woff += (j < w) ? s_w[j] : 0;
    total = s_w[0] + s_w[1] + s_w[2] + s_w[3];
    __syncthreads();
    return woff + inc - v;
}

// ---------------------------------------------------------------------------
// 2) One block per ROI: exclusive scan of its chunk hist + global ROI offset.
// ---------------------------------------------------------------------------
__global__ __launch_bounds__(256) void chunk_scan_kernel(
    int* __restrict__ H, const int* __restrict__ counts, int* __restrict__ offs, int nC)
{
    __shared__ int s_w[4];
    __shared__ int s_scan[RROI];
    const int r = blockIdx.x, tid = threadIdx.x;
    int tot;
    int e = block_scan256(counts[tid], tot, s_w, tid);
    s_scan[tid] = e;
    __syncthreads();
    const int off = s_scan[r];
    int v0 = (tid < nC) ? H[r * nC + tid] : 0;
    int t0;
    int e0 = block_scan256(v0, t0, s_w, tid);
    if (tid < nC) H[r * nC + tid] = off + e0;
    int c2 = 256 + tid;
    int v1 = (c2 < nC) ? H[r * nC + c2] : 0;
    int t1;
    int e1 = block_scan256(v1, t1, s_w, tid);
    if (c2 < nC) H[r * nC + c2] = off + t0 + e1;
    if (tid == 0) offs[r] = off;
}

// ---------------------------------------------------------------------------
// 3) Stable scatter (verified round 2).
// ---------------------------------------------------------------------------
__global__ __launch_bounds__(256) void scatter_kernel(
    const int* __restrict__ idx, const float* __restrict__ coords,
    const int* __restrict__ H, int* __restrict__ sGid,
    float* __restrict__ sXc, float* __restrict__ sYc, float* __restrict__ sZc,
    int N, int nC)
{
    __shared__ int s_base[RROI];
    const int c = blockIdx.x, tid = threadIdx.x;
    const int lane = tid & 63, wid = tid >> 6;
    s_base[tid] = H[tid * nC + c];
    int roiA[4]; float cxA[4], cyA[4], czA[4]; bool valA[4];
    #pragma unroll
    for (int j = 0; j < 4; j++) {
        int p = c * CHUNK + j * 256 + tid;
        bool v = p < N;
        valA[j] = v;
        roiA[j] = v ? idx[p] : 0;
        float x = 0.f, y = 0.f, z = 0.f;
        if (v) { x = coords[(size_t)p*3]; y = coords[(size_t)p*3+1]; z = coords[(size_t)p*3+2]; }
        cxA[j] = x; cyA[j] = y; czA[j] = z;
    }
    __syncthreads();
    #pragma unroll
    for (int j = 0; j < 4; j++) {
        #pragma unroll
        for (int w = 0; w < 4; w++) {
            if (wid == w) {
                bool v = valA[j];
                int roi = roiA[j];
                unsigned long long vm = __ballot(v);
                unsigned long long match = vm;
                #pragma unroll
                for (int b = 0; b < 8; b++) {
                    unsigned long long vote = __ballot((roi >> b) & 1);
                    match &= ((roi >> b) & 1) ? vote : ~vote;
                }
                int leader = match ? (__ffsll(match) - 1) : 0;
                int gsz  = (int)__popcll(match);
                int rank = (int)__popcll(match & ((1ull << lane) - 1ull));
                int basev = 0;
                if (match && lane == leader) {
                    basev = s_base[roi];
                    s_base[roi] = basev + gsz;
                }
                basev = __shfl(basev, leader);
                if (v) {
                    int dest = basev + rank;
                    int p = c * CHUNK + j * 256 + tid;
                    sGid[dest] = p;
                    sXc[dest] = cxA[j]; sYc[dest] = cyA[j]; sZc[dest] = czA[j];
                }
            }
            __syncthreads();
        }
    }
}

// ---------------------------------------------------------------------------
// 4) FPS per ROI + feature gather (verified round 2).
// ---------------------------------------------------------------------------
__global__ __launch_bounds__(512) void fps_feat_kernel(
    const int* __restrict__ offs, const int* __restrict__ counts,
    const float* __restrict__ sXc, const float* __restrict__ sYc,
    const float* __restrict__ sZc, const int* __restrict__ sGid,
    const float* __restrict__ feats, float* __restrict__ feat_out)
{
    __shared__ float sx[CAP], sy[CAP], sz[CAP];
    __shared__ int   sg[CAP];
    __shared__ int   s_samp[K_SAMP];
    __shared__ float s_rv[8];
    __shared__ int   s_ri[8];
    __shared__ int   s_last;

    const int r = blockIdx.x, tid = threadIdx.x;
    const int lane = tid & 63, wid = tid >> 6;
    const int off = offs[r];
    int count = counts[r]; if (count > CAP) count = CAP;

    float rx[8], ry[8], rz[8], rd[8];
    #pragma unroll
    for (int j = 0; j < 8; j++) {
        int i = j * 512 + tid;
        bool v = i < count;
        float x = 0.f, y = 0.f, z = 0.f;
        if (v) {
            x = sXc[off + i]; y = sYc[off + i]; z = sZc[off + i];
            sg[i] = sGid[off + i];
        }
        rx[j] = x; ry[j] = y; rz[j] = z;
        rd[j] = v ? 1e10f : -1.0f;
        sx[i] = x; sy[i] = y; sz[i] = z;
    }
    if (tid == 0) { s_samp[0] = 0; s_last = 0; }
    __syncthreads();

    if (count > 0) {
        int last = 0;
        for (int k = 1; k < K_SAMP; k++) {
            float lx = sx[last], ly = sy[last], lz = sz[last];
            float bv = -3.0e38f; int bi = 0x7fffffff;
            #pragma unroll
            for (int j = 0; j < 8; j++) {
                float dx = rx[j] - lx, dy = ry[j] - ly, dz = rz[j] - lz;
                float d = __fadd_rn(__fadd_rn(__fmul_rn(dx,dx), __fmul_rn(dy,dy)),
                                    __fmul_rn(dz,dz));
                float nd = fminf(rd[j], d);
                rd[j] = nd;
                int i = j * 512 + tid;
                if (nd > bv || (nd == bv && i < bi)) { bv = nd; bi = i; }
            }
            #pragma unroll
            for (int m = 32; m > 0; m >>= 1) {
                float ov = __shfl_xor(bv, m);
                int   oi = __shfl_xor(bi, m);
                if (ov > bv || (ov == bv && oi < bi)) { bv = ov; bi = oi; }
            }
            if (lane == 0) { s_rv[wid] = bv; s_ri[wid] = bi; }
            __syncthreads();
            if (tid == 0) {
                #pragma unroll
                for (int j = 1; j < 8; j++)
                    if (s_rv[j] > bv || (s_rv[j] == bv && s_ri[j] < bi)) {
                        bv = s_rv[j]; bi = s_ri[j];
                    }
                s_samp[k] = bi; s_last = bi;
            }
            __syncthreads();
            last = s_last;
        }
    }
    __syncthreads();

    for (int t = tid; t < FROW; t += 512) {
        int s = t / NFEAT;
        int f = t - s * NFEAT;
        float v = 0.f;
        if (count > 0) {
            int gid = sg[s_samp[s]];
            v = feats[(size_t)gid * NFEAT + f];
        }
        feat_out[(size_t)r * FROW + t] = v;
    }
}

// ---------------------------------------------------------------------------
// 5) L1 split-K GEMM: P[z] = feat * w1 (K-slice z). No atomics, no memset:
//    each slice writes its own partial buffer with coalesced float4 stores.
//    Tile math identical to the verified round-2 gemm_splitk. N fixed = 256.
// ---------------------------------------------------------------------------
__global__ __launch_bounds__(256) void gemm1_splitk_kernel(
    const float* __restrict__ A, const float* __restrict__ B, float* __restrict__ P,
    int Kdim, int kc)
{
    __shared__ float As[16][64];
    __shared__ float Bs[16][64];
    const int tid = threadIdx.x;
    const int bm  = blockIdx.y * 64;
    const int bn  = blockIdx.x * 64;
    const int k0  = blockIdx.z * kc;
    const int k1  = (k0 + kc < Kdim) ? (k0 + kc) : Kdim;
    const int ty  = tid >> 4, tx = tid & 15;
    const int am  = tid >> 2, ak = (tid & 3) * 4;
    const int bk  = tid >> 6, bnn = tid & 63;

    float acc[4][4] = {};
    for (int k = k0; k < k1; k += 16) {
        int arow = bm + am;
        float4 av;
        if (k + ak + 3 < Kdim) {
            av = *reinterpret_cast<const float4*>(A + (size_t)arow * Kdim + k + ak);
        } else {
            av.x = (k+ak+0 < Kdim) ? A[(size_t)arow*Kdim + k+ak+0] : 0.f;
            av.y = (k+ak+1 < Kdim) ? A[(size_t)arow*Kdim + k+ak+1] : 0.f;
            av.z = (k+ak+2 < Kdim) ? A[(size_t)arow*Kdim + k+ak+2] : 0.f;
            av.w = (k+ak+3 < Kdim) ? A[(size_t)arow*Kdim + k+ak+3] : 0.f;
        }
        As[ak+0][am] = av.x; As[ak+1][am] = av.y;
        As[ak+2][am] = av.z; As[ak+3][am] = av.w;
        #pragma unroll
        for (int j = 0; j < 4; j++) {
            int kr = bk + j * 4;
            Bs[kr][bnn] = (k + kr < Kdim) ? B[(size_t)(k + kr) * 256 + bn + bnn] : 0.f;
        }
        __syncthreads();
        #pragma unroll
        for (int kk = 0; kk < 16; kk++) {
            float4 aq = *reinterpret_cast<const float4*>(&As[kk][ty * 4]);
            float4 bq = *reinterpret_cast<const float4*>(&Bs[kk][tx * 4]);
            float a[4] = {aq.x, aq.y, aq.z, aq.w};
            float b[4] = {bq.x, bq.y, bq.z, bq.w};
            #pragma unroll
            for (int i = 0; i < 4; i++)
                #pragma unroll
                for (int j = 0; j < 4; j++)
                    acc[i][j] = fmaf(a[i], b[j], acc[i][j]);
        }
        __syncthreads();
    }
    float* Pz = P + (size_t)blockIdx.z * 65536;
    #pragma unroll
    for (int i = 0; i < 4; i++) {
        float4 o = {acc[i][0], acc[i][1], acc[i][2], acc[i][3]};
        *reinterpret_cast<float4*>(&Pz[(size_t)(bm + ty*4 + i) * 256 + bn + tx*4]) = o;
    }
}

// ---------------------------------------------------------------------------
// Shared BN epilogue: thread owns column (bn+lane), rows w*32..w*32+31 in
// acc[32]. Two LDS reduce rounds (mean, var), then normalize + store
// coalesced (per row, 64 consecutive floats per wave).
// ---------------------------------------------------------------------------
__device__ __forceinline__ void bn_store(
    float (&acc)[32], const float* __restrict__ g, const float* __restrict__ be,
    float* __restrict__ Y, int NC, int bn, int relu,
    float (*red)[64], int lane, int w)
{
    float s = 0.f;
    #pragma unroll
    for (int i = 0; i < 32; i++) s += acc[i];
    red[w][lane] = s;
    __syncthreads();
    float m = 0.f;
    #pragma unroll
    for (int j = 0; j < 8; j++) m += red[j][lane];
    m *= (1.f / 256.f);
    float q = 0.f;
    #pragma unroll
    for (int i = 0; i < 32; i++) { float d = acc[i] - m; q += d * d; }
    __syncthreads();
    red[w][lane] = q;
    __syncthreads();
    float v = 0.f;
    #pragma unroll
    for (int j = 0; j < 8; j++) v += red[j][lane];
    v *= (1.f / 256.f);
    float sc = g[bn + lane] * rsqrtf(v + 1e-5f);
    float bi = be[bn + lane];
    #pragma unroll
    for (int i = 0; i < 32; i++) {
        float y = (acc[i] - m) * sc + bi;
        if (relu) y = fmaxf(y, 0.f);
        Y[(size_t)(w * 32 + i) * NC + bn + lane] = y;
    }
}

// ---------------------------------------------------------------------------
// 6) Sum 16 L1 partials + BN + ReLU -> y1. Grid 4 blocks x 512 threads.
// ---------------------------------------------------------------------------
__global__ __launch_bounds__(512) void sum_bn_kernel(
    const float* __restrict__ P, const float* __restrict__ g,
    const float* __restrict__ be, float* __restrict__ Y)
{
    __shared__ float red[8][64];
    const int tid = threadIdx.x, lane = tid & 63, w = tid >> 6;
    const int bn = blockIdx.x * 64;
    float acc[32];
    #pragma unroll
    for (int i = 0; i < 32; i++) acc[i] = 0.f;
    for (int z = 0; z < 16; z++) {
        const float* Pz = P + (size_t)z * 65536;
        #pragma unroll
        for (int i = 0; i < 32; i++)
            acc[i] += Pz[(size_t)(w * 32 + i) * 256 + bn + lane];
    }
    bn_store(acc, g, be, Y, 256, bn, 1, red, lane, w);
}

// ---------------------------------------------------------------------------
// 7) Fused full-K GEMM + BN (+ReLU): block = all 256 rows x 64-col stripe.
//    512 threads: wave w -> rows w*32..+31, lane -> column bn+lane.
// ---------------------------------------------------------------------------
template<int KD, int NC, int RELU>
__global__ __launch_bounds__(512) void gemm_bn_kernel(
    const float* __restrict__ A, const float* __restrict__ B,
    const float* __restrict__ g, const float* __restrict__ be,
    float* __restrict__ Y)
{
    __shared__ float As[16][260];   // [kk][row], +4 pad -> 2-way banks (free)
    __shared__ float Bs[16][64];    // [kk][col]
    __shared__ float red[8][64];
    const int tid  = threadIdx.x;
    const int lane = tid & 63;
    const int w    = tid >> 6;
    const int bn   = blockIdx.x * 64;
    const int r    = tid >> 1;          // A-stage row (0..255)
    const int hf   = (tid & 1) * 8;     // A-stage k offset (0 or 8)
    const int bkk  = tid >> 5;          // B-stage kk (0..15)
    const int bc   = (tid & 31) * 2;    // B-stage col pair

    float acc[32];
    #pragma unroll
    for (int i = 0; i < 32; i++) acc[i] = 0.f;

    for (int k0 = 0; k0 < KD; k0 += 16) {   // KD multiple of 16
        float4 a0 = *reinterpret_cast<const float4*>(A + (size_t)r * KD + k0 + hf);
        float4 a1 = *reinterpret_cast<const float4*>(A + (size_t)r * KD + k0 + hf + 4);
        float2 bv = *reinterpret_cast<const float2*>(B + (size_t)(k0 + bkk) * NC + bn + bc);
        __syncthreads();   // previous inner loop done before overwrite
        As[hf+0][r] = a0.x; As[hf+1][r] = a0.y; As[hf+2][r] = a0.z; As[hf+3][r] = a0.w;
        As[hf+4][r] = a1.x; As[hf+5][r] = a1.y; As[hf+6][r] = a1.z; As[hf+7][r] = a1.w;
        Bs[bkk][bc] = bv.x; Bs[bkk][bc+1] = bv.y;
        __syncthreads();
        #pragma unroll
        for (int kk = 0; kk < 16; kk++) {
            float b = Bs[kk][lane];
            #pragma unroll
            for (int i2 = 0; i2 < 8; i2++) {
                float4 a = *reinterpret_cast<const float4*>(&As[kk][w * 32 + i2 * 4]);
                acc[i2*4+0] = fmaf(a.x, b, acc[i2*4+0]);
                acc[i2*4+1] = fmaf(a.y, b, acc[i2*4+1]);
                acc[i2*4+2] = fmaf(a.z, b, acc[i2*4+2]);
                acc[i2*4+3] = fmaf(a.w, b, acc[i2*4+3]);
            }
        }
    }
    __syncthreads();
    bn_store(acc, g, be, Y, NC, bn, RELU, red, lane, w);
}

// ---------------------------------------------------------------------------
extern "C" void kernel_launch(void* const* d_in, const int* in_sizes, int n_in,
                              void* d_out, int out_size, void* d_ws, size_t ws_size,
                              hipStream_t stream)
{
    (void)n_in; (void)out_size; (void)ws_size;
    const int*   idx    = (const int*)  d_in[1];
    const float* feats  = (const float*)d_in[2];
    const float* coords = (const float*)d_in[3];
    const float* w1 = (const float*)d_in[4];
    const float* g1 = (const float*)d_in[6];  const float* be1 = (const float*)d_in[7];
    const float* w2 = (const float*)d_in[8];
    const float* g2 = (const float*)d_in[10]; const float* be2 = (const float*)d_in[11];
    const float* w3 = (const float*)d_in[12];
    const float* g3 = (const float*)d_in[14]; const float* be3 = (const float*)d_in[15];
    const float* w4 = (const float*)d_in[16];
    const float* g4 = (const float*)d_in[18]; const float* be4 = (const float*)d_in[19];
    const float* w5 = (const float*)d_in[20];
    const float* g5 = (const float*)d_in[22]; const float* be5 = (const float*)d_in[23];
    const int N  = in_sizes[1];
    const int nC = (N + CHUNK - 1) / CHUNK;

    float* ws   = (float*)d_ws;
    float* feat = ws;                        // 1,152,000
    float* P    = ws + 1152000;              // 16 * 65536 = 1,048,576
    float* y1   = P + 1048576;               // 65536
    float* y2   = y1 + 65536;                // 65536
    float* y3   = y2 + 65536;                // 131072
    float* y4   = y3 + 131072;               // 65536
    int*   counts = (int*)(y4 + 65536);      // 256
    int*   offs   = counts + 256;            // 256
    int*   H      = offs + 256;              // up to 256*1024
    int*   sGid   = H + 256 * 1024;          // N
    float* sXc    = (float*)(sGid + N);      // N
    float* sYc    = sXc + N;                 // N
    float* sZc    = sYc + N;                 // N
    float* out    = (float*)d_out;

    hipMemsetAsync(counts, 0, 256 * sizeof(int), stream);

    hist_kernel      <<<nC,  256, 0, stream>>>(idx, H, counts, N, nC);
    chunk_scan_kernel<<<256, 256, 0, stream>>>(H, counts, offs, nC);
    scatter_kernel   <<<nC,  256, 0, stream>>>(idx, coords, H, sGid, sXc, sYc, sZc, N, nC);
    fps_feat_kernel  <<<256, 512, 0, stream>>>(offs, counts, sXc, sYc, sZc, sGid, feats, feat);

    gemm1_splitk_kernel<<<dim3(4,4,16), 256, 0, stream>>>(feat, w1, P, 4500, 288);
    sum_bn_kernel      <<<4, 512, 0, stream>>>(P, g1, be1, y1);
    gemm_bn_kernel<256,256,1><<<4, 512, 0, stream>>>(y1, w2, g2, be2, y2);
    gemm_bn_kernel<256,512,0><<<8, 512, 0, stream>>>(y2, w3, g3, be3, y3);
    gemm_bn_kernel<512,256,1><<<4, 512, 0, stream>>>(y3, w4, g4, be4, y4);
    gemm_bn_kernel<256,512,1><<<8, 512, 0, stream>>>(y4, w5, g5, be5, out);
}